// Round 3
// baseline (843.783 us; speedup 1.0000x reference)
//
#include <hip/hip_runtime.h>
#include <hip/hip_bf16.h>

// B=64, C=32, V=1024, L=12, ORDER=2
// R2 restructuring: W_k(x·G_k) = (W_k x)·G_k  =>
//   Y0[m][v]  = sum_c W[o][c]        x[b,c,v,l],   m = b*384 + o*12 + l
//   Ycat[m][k*1024+v] = sum_c W[o][32(k+1)+c] x[b,c,v,l],  k=0..5
//   out[b,o,w,l] = bias[o] + Y0[m][w] + sum_{k,v} Ycat[m][(k,v)]*G_k[v][w]
// Single GEMM M=24576 N=1024 K=6144 writes d_out directly (no R, no mix).
// BtCat2[w][k*1024+v] = G_k[v][w], G = {A1, A1^2, A2, A2^2, adp, adp^2}.

typedef __attribute__((ext_vector_type(8))) short short8;
typedef __attribute__((ext_vector_type(4))) float floatx4;

#define V_DIM 1024
#define L_DIM 12
#define B_DIM 64
#define C_DIM 32
#define KCAT 6144

// ---------------- adp: relu + row softmax --------------------------------
__global__ __launch_bounds__(128) void adp_kernel(
    const float* __restrict__ nv1, const float* __restrict__ nv2,
    float* __restrict__ adp) {
  const int v = blockIdx.x, tid = threadIdx.x;
  float n1[10];
#pragma unroll
  for (int i = 0; i < 10; ++i) n1[i] = nv1[v * 10 + i];
  __shared__ float red[128];
  float e[8];
  float lmax = -1e30f;
#pragma unroll
  for (int j = 0; j < 8; ++j) {
    int w = tid + j * 128;
    float s = 0.f;
#pragma unroll
    for (int i = 0; i < 10; ++i) s += n1[i] * nv2[i * V_DIM + w];
    s = fmaxf(s, 0.f);
    e[j] = s;
    lmax = fmaxf(lmax, s);
  }
  red[tid] = lmax; __syncthreads();
  for (int s = 64; s > 0; s >>= 1) {
    if (tid < s) red[tid] = fmaxf(red[tid], red[tid + s]);
    __syncthreads();
  }
  float mx = red[0]; __syncthreads();
  float lsum = 0.f;
#pragma unroll
  for (int j = 0; j < 8; ++j) { e[j] = __expf(e[j] - mx); lsum += e[j]; }
  red[tid] = lsum; __syncthreads();
  for (int s = 64; s > 0; s >>= 1) {
    if (tid < s) red[tid] += red[tid + s];
    __syncthreads();
  }
  float inv = 1.f / red[0];
#pragma unroll
  for (int j = 0; j < 8; ++j) adp[(size_t)v * V_DIM + tid + j * 128] = e[j] * inv;
}

// ------------- cast supports to bf16: straight + transposed ---------------
// straight -> As[z] (row-major a), transposed -> BtCat2 col-block 2z*1024
__global__ __launch_bounds__(256) void cast_transpose(
    const float* __restrict__ A1, const float* __restrict__ A2,
    const float* __restrict__ adp, __hip_bfloat16* __restrict__ As,
    __hip_bfloat16* __restrict__ BtCat2) {
  const int z = blockIdx.z;
  const float* src = (z == 0) ? A1 : (z == 1) ? A2 : adp;
  __hip_bfloat16* sdst = As + (size_t)z * V_DIM * V_DIM;
  __hip_bfloat16* tdst = BtCat2 + (size_t)(2 * z) * V_DIM;  // col offset, ld=6144
  __shared__ float tile[64][65];
  const int v0 = blockIdx.y * 64, w0 = blockIdx.x * 64;
  const int tc = threadIdx.x & 15, tr = threadIdx.x >> 4;
#pragma unroll
  for (int i = 0; i < 4; ++i) {
    int r = tr + i * 16;
    float4 val = *(const float4*)(src + (size_t)(v0 + r) * V_DIM + w0 + tc * 4);
    tile[r][tc * 4 + 0] = val.x; tile[r][tc * 4 + 1] = val.y;
    tile[r][tc * 4 + 2] = val.z; tile[r][tc * 4 + 3] = val.w;
    __hip_bfloat16* sp = sdst + (size_t)(v0 + r) * V_DIM + w0 + tc * 4;
    sp[0] = __float2bfloat16(val.x); sp[1] = __float2bfloat16(val.y);
    sp[2] = __float2bfloat16(val.z); sp[3] = __float2bfloat16(val.w);
  }
  __syncthreads();
#pragma unroll
  for (int i = 0; i < 4; ++i) {
    int r = tr + i * 16;  // output row = w0 + r
    __hip_bfloat16* tp = tdst + (size_t)(w0 + r) * KCAT + v0 + tc * 4;
#pragma unroll
    for (int j = 0; j < 4; ++j) tp[j] = __float2bfloat16(tile[tc * 4 + j][r]);
  }
}

// ------------- Y: channel-premix of x into Ycat + Y0 ----------------------
// x[b][c][v][l] fp32 -> Ycat[m][(k,v)] bf16 (k=0..5 -> W block k+1),
//                       Y0[m][v] bf16 (W block 0).  m = b*384 + o*12 + l.
__global__ __launch_bounds__(256, 3) void y_kernel(
    const float* __restrict__ x, const float* __restrict__ W,
    __hip_bfloat16* __restrict__ Ycat, __hip_bfloat16* __restrict__ Y0) {
  const int b = blockIdx.y, v0 = blockIdx.x * 64;
  const int tid = threadIdx.x;
  const int lane = tid & 63;
  const int wq = __builtin_amdgcn_readfirstlane(tid >> 6);
  __shared__ __hip_bfloat16 xs[768 * 33];  // [(l*64+v)*33 + c]
  // stage x: per c, 768 contiguous fp32 (v-tile x 12 l)
#pragma unroll
  for (int it = 0; it < 24; ++it) {
    int i = tid + it * 256;           // 6144 float4
    int c = i / 192, j = i - c * 192;
    float4 val = *(const float4*)(x + (size_t)(b * 32 + c) * 12288 + v0 * 12 + j * 4);
    int e = j * 4;
    float vv[4] = {val.x, val.y, val.z, val.w};
#pragma unroll
    for (int q = 0; q < 4; ++q) {
      int ee = e + q, v = ee / 12, l = ee - v * 12;
      xs[(l * 64 + v) * 33 + c] = __float2bfloat16(vv[q]);
    }
  }
  __syncthreads();
  for (int lp = 0; lp < 6; ++lp) {
    const int l = lp * 2;
    float xa[32], xb[32];
#pragma unroll
    for (int c = 0; c < 32; ++c) {
      xa[c] = __bfloat162float(xs[(l * 64 + lane) * 33 + c]);
      xb[c] = __bfloat162float(xs[((l + 1) * 64 + lane) * 33 + c]);
    }
    for (int oi = 0; oi < 8; ++oi) {
      const int o = wq * 8 + oi;                 // wave-uniform
      const float* Wr = W + o * 224;
      float aacc[7], bacc[7];
#pragma unroll
      for (int kk = 0; kk < 7; ++kk) { aacc[kk] = 0.f; bacc[kk] = 0.f; }
#pragma unroll
      for (int c = 0; c < 32; ++c) {
#pragma unroll
        for (int kk = 0; kk < 7; ++kk) {
          float wv = Wr[kk * 32 + c];            // uniform -> s_load
          aacc[kk] += wv * xa[c];
          bacc[kk] += wv * xb[c];
        }
      }
      const size_t row = (size_t)b * 384 + o * 12 + l;
      Y0[row * V_DIM + v0 + lane] = __float2bfloat16(aacc[0]);
      Y0[(row + 1) * V_DIM + v0 + lane] = __float2bfloat16(bacc[0]);
#pragma unroll
      for (int kk = 1; kk < 7; ++kk) {
        Ycat[row * KCAT + (kk - 1) * V_DIM + v0 + lane] = __float2bfloat16(aacc[kk]);
        Ycat[(row + 1) * KCAT + (kk - 1) * V_DIM + v0 + lane] = __float2bfloat16(bacc[kk]);
      }
    }
  }
}

// ---------------- MFMA GEMM: C = A * Bt^T over K --------------------------
// A [.,lda] bf16 rm, Bt [.,ldb] bf16 rm. MODE 0: C bf16 [m*ldc+n].
// MODE 2: final epilogue -> out fp32 [b,o,w,l] += Y0 + bias.
__device__ __forceinline__ void gll16(const __hip_bfloat16* g, __hip_bfloat16* l) {
  __builtin_amdgcn_global_load_lds(
      (const __attribute__((address_space(1))) void*)g,
      (__attribute__((address_space(3))) void*)l, 16, 0, 0);
}

template <int MODE>
__global__ __launch_bounds__(256) void gemm_k(
    const __hip_bfloat16* __restrict__ Abase,
    const __hip_bfloat16* __restrict__ Btbase,
    __hip_bfloat16* __restrict__ Cbase, float* __restrict__ outp,
    const __hip_bfloat16* __restrict__ Y0, const float* __restrict__ bias,
    int K, int lda, int ldb, int ldc,
    long long aStride, long long bStride, long long cStride) {
  const __hip_bfloat16* A = Abase + (size_t)blockIdx.z * aStride;
  const __hip_bfloat16* Bt = Btbase + (size_t)blockIdx.z * bStride;
  __hip_bfloat16* C = Cbase + (size_t)blockIdx.z * cStride;
  __shared__ __align__(16) __hip_bfloat16 lA[128 * 64];
  __shared__ __align__(16) __hip_bfloat16 lB[128 * 64];
  const int tid = threadIdx.x;
  const int wv = tid >> 6, lane = tid & 63;
  const int wm = wv >> 1, wn = wv & 1;
  const int m0 = blockIdx.y * 128, n0 = blockIdx.x * 128;
  const int lrow = lane >> 3, lcol = lane & 7;
  const int gcol = lcol ^ (lrow & 7);           // XOR bank swizzle (R1)
  const int fr = lane & 15, quad = lane >> 4;
  const int sw = fr & 7;

  floatx4 acc[4][4];
#pragma unroll
  for (int i = 0; i < 4; ++i)
#pragma unroll
    for (int j = 0; j < 4; ++j) acc[i][j] = (floatx4){0.f, 0.f, 0.f, 0.f};

  for (int kt = 0; kt < K; kt += 64) {
    __syncthreads();
#pragma unroll
    for (int i = 0; i < 4; ++i) {
      int r0 = (wv * 4 + i) * 8;
      gll16(A + (size_t)(m0 + r0 + lrow) * lda + kt + gcol * 8, &lA[r0 * 64]);
      gll16(Bt + (size_t)(n0 + r0 + lrow) * ldb + kt + gcol * 8, &lB[r0 * 64]);
    }
    __syncthreads();
#pragma unroll
    for (int ks = 0; ks < 2; ++ks) {
      const int chunk = (ks * 4 + quad) ^ sw;
      short8 af[4], bfr[4];
#pragma unroll
      for (int t = 0; t < 4; ++t) {
        af[t] = *(const short8*)&lA[(wm * 64 + t * 16 + fr) * 64 + chunk * 8];
        bfr[t] = *(const short8*)&lB[(wn * 64 + t * 16 + fr) * 64 + chunk * 8];
      }
#pragma unroll
      for (int i = 0; i < 4; ++i)
#pragma unroll
        for (int j = 0; j < 4; ++j)
          acc[i][j] = __builtin_amdgcn_mfma_f32_16x16x32_bf16(af[i], bfr[j], acc[i][j], 0, 0, 0);
    }
  }
  // epilogue: C/D layout col=lane&15, row=quad*4+reg (m89-verified)
#pragma unroll
  for (int i = 0; i < 4; ++i) {
    const int mb = m0 + wm * 64 + i * 16 + quad * 4;  // 4-aligned
    int bq = 0, oq = 0, lq = 0;
    float bs = 0.f;
    if (MODE == 2) {
      bq = mb / 384;
      int olq = mb - bq * 384;
      oq = olq / 12;
      lq = olq - oq * 12;            // in {0,4,8}: 4-run never crosses o
      bs = bias[oq];
    }
#pragma unroll
    for (int j = 0; j < 4; ++j) {
      const int n = n0 + wn * 64 + j * 16 + fr;
      if (MODE == 0) {
#pragma unroll
        for (int r = 0; r < 4; ++r)
          C[(size_t)(mb + r) * ldc + n] = __float2bfloat16(acc[i][j][r]);
      } else {
        float4 val;
        float* vp = &val.x;
#pragma unroll
        for (int r = 0; r < 4; ++r)
          vp[r] = acc[i][j][r] + bs +
                  __bfloat162float(Y0[(size_t)(mb + r) * V_DIM + n]);
        *(float4*)&outp[(size_t)bq * 393216 + (size_t)oq * 12288 +
                        (size_t)n * 12 + lq] = val;
      }
    }
  }
}

// --------------------------- launcher ------------------------------------
extern "C" void kernel_launch(void* const* d_in, const int* in_sizes, int n_in,
                              void* d_out, int out_size, void* d_ws,
                              size_t ws_size, hipStream_t stream) {
  const float* x = (const float*)d_in[0];
  const float* A1 = (const float*)d_in[1];
  const float* A2 = (const float*)d_in[2];
  const float* nv1 = (const float*)d_in[3];
  const float* nv2 = (const float*)d_in[4];
  const float* W = (const float*)d_in[5];
  const float* bias = (const float*)d_in[6];
  float* out = (float*)d_out;

  char* ws = (char*)d_ws;
  // ws: Ycat 301,989,888 | Y0 50,331,648 | BtCat2 12,582,912 |
  //     As 6,291,456 | adp 4,194,304  => 375,390,208 B (same as R1)
  __hip_bfloat16* Ycat = (__hip_bfloat16*)(ws + 0);
  __hip_bfloat16* Y0 = (__hip_bfloat16*)(ws + 301989888ull);
  __hip_bfloat16* BtCat2 = (__hip_bfloat16*)(ws + 352321536ull);
  __hip_bfloat16* As = (__hip_bfloat16*)(ws + 364904448ull);
  float* adp = (float*)(ws + 371195904ull);

  // 1. adaptive adjacency
  adp_kernel<<<dim3(1024), dim3(128), 0, stream>>>(nv1, nv2, adp);
  // 2. bf16 casts: straight (As) + transposed into BtCat2 col-blocks 0,2,4
  cast_transpose<<<dim3(16, 16, 3), dim3(256), 0, stream>>>(A1, A2, adp, As, BtCat2);
  // 3. squares into BtCat2 col-blocks 1,3,5:
  //    C[w][v] = sum_u a^T[w,u] * a[v,u] = (a^2)^T[w][v]
  gemm_k<0><<<dim3(8, 8, 3), dim3(256), 0, stream>>>(
      BtCat2, As, BtCat2 + 1024, nullptr, nullptr, nullptr,
      1024, KCAT, 1024, KCAT, 2048ll, 1048576ll, 2048ll);
  // 4. channel premix: x -> Ycat (6 slices) + Y0
  y_kernel<<<dim3(16, 64), dim3(256), 0, stream>>>(x, W, Ycat, Y0);
  // 5. fused diffusion+output GEMM: out = Ycat @ BtCat2^T + Y0 + bias
  gemm_k<2><<<dim3(8, 192), dim3(256), 0, stream>>>(
      Ycat, BtCat2, nullptr, out, Y0, bias,
      KCAT, KCAT, KCAT, 0, 0ll, 0ll, 0ll);
}